// Round 3
// baseline (219.963 us; speedup 1.0000x reference)
//
#include <hip/hip_runtime.h>

// LIF spike recurrence over T axis.
// x: [B=32, T=8, C=128, H=32, W=32] fp32, out: same shape (0/1 spikes).
// mem = mem*0.5 + x_t; spike = (mem > 1.0); mem = spike ? 0 : mem.
//
// Structure: each thread handles 2 column-groups (4 contiguous W floats each),
// per group: 8 NT loads -> full recurrence in regs -> 8 NT stores.
// Loads and stores are NOT interleaved (shared vmcnt counter would make
// load-waits block on store retirement). 2048 blocks x 256 thr with
// launch_bounds(256,8) -> 8 blocks/CU resident, single wave batch.

#define TT 8
#define INNER4 (128 * 32 * 32 / 4)   // C*H*W in float4 units = 32768
#define NTHREADS (2048 * 256)        // 524288 threads, 2 column-groups each

typedef float v4f __attribute__((ext_vector_type(4)));

__global__ __launch_bounds__(256, 8) void lif_kernel(
    const v4f* __restrict__ x, v4f* __restrict__ out) {
    int tid = blockIdx.x * blockDim.x + threadIdx.x;

#pragma unroll
    for (int phase = 0; phase < 2; ++phase) {
        int col = tid + phase * NTHREADS;   // 0 .. 2^20-1
        int b = col >> 15;                  // col / INNER4
        int i = col & (INNER4 - 1);         // col % INNER4
        int base = b * (TT * INNER4) + i;   // float4 offset of (b, t=0, i)

        // Phase A: all loads in flight (independent addresses)
        v4f xv[TT];
#pragma unroll
        for (int t = 0; t < TT; ++t)
            xv[t] = __builtin_nontemporal_load(x + base + t * INNER4);

        // Phase B: recurrence, spikes written in-place over xv (keeps VGPRs low)
        v4f mem = {0.f, 0.f, 0.f, 0.f};
#pragma unroll
        for (int t = 0; t < TT; ++t) {
            mem = mem * 0.5f + xv[t];
            v4f sp;
            sp.x = (mem.x > 1.0f) ? 1.0f : 0.0f;
            sp.y = (mem.y > 1.0f) ? 1.0f : 0.0f;
            sp.z = (mem.z > 1.0f) ? 1.0f : 0.0f;
            sp.w = (mem.w > 1.0f) ? 1.0f : 0.0f;
            mem.x = (mem.x > 1.0f) ? 0.0f : mem.x;
            mem.y = (mem.y > 1.0f) ? 0.0f : mem.y;
            mem.z = (mem.z > 1.0f) ? 0.0f : mem.z;
            mem.w = (mem.w > 1.0f) ? 0.0f : mem.w;
            xv[t] = sp;
        }

        // Phase C: all stores (fire-and-forget, never gate compute)
#pragma unroll
        for (int t = 0; t < TT; ++t)
            __builtin_nontemporal_store(xv[t], out + base + t * INNER4);
    }
}

extern "C" void kernel_launch(void* const* d_in, const int* in_sizes, int n_in,
                              void* d_out, int out_size, void* d_ws, size_t ws_size,
                              hipStream_t stream) {
    const v4f* x = (const v4f*)d_in[0];
    v4f* out = (v4f*)d_out;

    const int block = 256;
    const int grid = 2048;   // 8 blocks/CU, single resident batch
    lif_kernel<<<grid, block, 0, stream>>>(x, out);
}